// Round 5
// baseline (205.318 us; speedup 1.0000x reference)
//
#include <hip/hip_runtime.h>

typedef unsigned short ushort_t;
typedef __bf16 bf16x8 __attribute__((ext_vector_type(8)));
typedef unsigned short ushortx8 __attribute__((ext_vector_type(8)));
typedef unsigned short ushortx4 __attribute__((ext_vector_type(4)));
typedef unsigned int uintx4 __attribute__((ext_vector_type(4)));
typedef float floatx4 __attribute__((ext_vector_type(4)));
typedef float floatx16 __attribute__((ext_vector_type(16)));

__device__ inline void load16_lds(const ushort_t* g, ushort_t* l) {
  __builtin_amdgcn_global_load_lds(
      (__attribute__((address_space(1))) void*)(g),
      (__attribute__((address_space(3))) void*)(l),
      16, 0, 0);
}

__device__ inline float bf2f(ushort_t u) {
  unsigned int v = ((unsigned int)u) << 16;
  return __builtin_bit_cast(float, v);
}

__device__ inline ushort_t f2bf(float f) {
  unsigned int u = __builtin_bit_cast(unsigned int, f);
  u += 0x7fffu + ((u >> 16) & 1u);
  return (ushort_t)(u >> 16);
}

__device__ inline bf16x8 ldfrag(const ushort_t* p) {
  return __builtin_bit_cast(bf16x8, *(const ushortx8*)p);
}

// pack two f32 -> one u32 of 2 bf16 (lo = first arg); no builtin on gfx950.
__device__ inline unsigned cvtpk_bf16(float lo, float hi) {
  unsigned r;
  asm("v_cvt_pk_bf16_f32 %0, %1, %2" : "=v"(r) : "v"(lo), "v"(hi));
  return r;
}

// exchange one 32-lane half of a with the complementary half of b.
// Arg order follows HK/m214-v22 (verified on HW with the same crow layout):
// first = pk of kv-pair (+0,+1), second = pk of kv-pair (+8,+9).
__device__ inline void plswap(unsigned& a, unsigned& b) {
  asm("v_permlane32_swap_b32 %0, %1" : "+v"(a), "+v"(b));
}

// per-wave dtype sniff; P(wrong | fp32) ~= 0.55^64 ~= 4e-17.
__device__ inline bool sniff_f32(const ushort_t* x, int lane_off) {
  float v = fabsf(bf2f(x[lane_off]));
  bool big = !(v < 1e4f);
  return __ballot(big) != 0ull;
}

// ---------------------------------------------------------------------------
// Canonicalize inputs to bf16 (x, Wq, Wk, Wv) and fp32 biases; inline sniff.
// ---------------------------------------------------------------------------
__global__ __launch_bounds__(256) void convert_all(
    const void* __restrict__ x,
    const void* __restrict__ wq, const void* __restrict__ wk, const void* __restrict__ wv,
    const void* __restrict__ bq, const void* __restrict__ bk, const void* __restrict__ bv,
    ushort_t* __restrict__ xb, ushort_t* __restrict__ wqb,
    ushort_t* __restrict__ wkb, ushort_t* __restrict__ wvb,
    float* __restrict__ biasf, int* __restrict__ flag)
{
  const bool f32 = sniff_f32((const ushort_t*)x, (int)(threadIdx.x & 63));
  const int seg = blockIdx.y;
  if (seg == 4) {
    if (blockIdx.x == 0 && threadIdx.x == 0) *flag = f32 ? 1 : 0;
    const int i = blockIdx.x * 256 + threadIdx.x;
    if (i >= 1024) return;
    const void* bs[3] = {bq, bk, bv};
#pragma unroll
    for (int k = 0; k < 3; ++k)
      biasf[k * 1024 + i] = f32 ? ((const float*)bs[k])[i] : bf2f(((const ushort_t*)bs[k])[i]);
    return;
  }
  const void* src = (seg == 0) ? x : (seg == 1) ? wq : (seg == 2) ? wk : wv;
  ushort_t* dst   = (seg == 0) ? xb : (seg == 1) ? wqb : (seg == 2) ? wkb : wvb;
  const int n = (seg == 0) ? 4194304 : 1048576;
  const int i = (blockIdx.x * 256 + threadIdx.x) * 8;
  if (i >= n) return;
  if (f32) {
    const float* s = (const float*)src + i;
    ushortx8 o;
#pragma unroll
    for (int j = 0; j < 8; ++j) o[j] = f2bf(s[j]);
    *(ushortx8*)(dst + i) = o;
  } else {
    *(ushortx8*)(dst + i) = *(const ushortx8*)((const ushort_t*)src + i);
  }
}

// ---------------------------------------------------------------------------
// QKV projection: out = x @ W^T + b; Q scaled by log2(e)/sqrt(64).
// which==2 (V) writes DIRECTLY in transposed layout Vt(bh,hs,s).
// ---------------------------------------------------------------------------
__global__ __launch_bounds__(256, 2) void qkv_gemm(
    const ushort_t* __restrict__ x,
    const ushort_t* __restrict__ Wq, const ushort_t* __restrict__ Wk,
    const ushort_t* __restrict__ Wv, const float* __restrict__ biasf,
    ushort_t* __restrict__ Qo, ushort_t* __restrict__ Ko, ushort_t* __restrict__ Vt)
{
  __shared__ __attribute__((aligned(16))) ushort_t As[128 * 32];
  __shared__ __attribute__((aligned(16))) ushort_t Bs[128 * 32];

  const int which = blockIdx.z;
  const ushort_t* W = (which == 0) ? Wq : (which == 1) ? Wk : Wv;
  const float oscale = (which == 0) ? 0.18033688011112042f : 1.0f;

  const int n0 = blockIdx.x * 128;
  const int m0 = blockIdx.y * 128;

  const int tid  = threadIdx.x;
  const int wave = tid >> 6;
  const int lane = tid & 63;
  const int ln   = lane & 15;
  const int quad = lane >> 4;
  const int wm = (wave >> 1) * 64;
  const int wn = (wave & 1) * 64;

  floatx4 acc[4][4];
#pragma unroll
  for (int i = 0; i < 4; ++i)
#pragma unroll
    for (int j = 0; j < 4; ++j) acc[i][j] = floatx4{0.f, 0.f, 0.f, 0.f};

  const int c1 = tid, c2 = tid + 256;
  const ushort_t* ga1 = x + (m0 + (c1 >> 2)) * 1024 + (c1 & 3) * 8;
  const ushort_t* ga2 = x + (m0 + (c2 >> 2)) * 1024 + (c2 & 3) * 8;
  const ushort_t* gb1 = W + (n0 + (c1 >> 2)) * 1024 + (c1 & 3) * 8;
  const ushort_t* gb2 = W + (n0 + (c2 >> 2)) * 1024 + (c2 & 3) * 8;
  ushort_t* la1 = As + wave * 512;
  ushort_t* la2 = As + 2048 + wave * 512;
  ushort_t* lb1 = Bs + wave * 512;
  ushort_t* lb2 = Bs + 2048 + wave * 512;

  for (int kt = 0; kt < 1024; kt += 32) {
    __syncthreads();
    load16_lds(ga1 + kt, la1);
    load16_lds(ga2 + kt, la2);
    load16_lds(gb1 + kt, lb1);
    load16_lds(gb2 + kt, lb2);
    __syncthreads();

    bf16x8 af[4], bfr[4];
#pragma unroll
    for (int mi = 0; mi < 4; ++mi)
      af[mi] = ldfrag(As + (wm + mi * 16 + ln) * 32 + quad * 8);
#pragma unroll
    for (int ni = 0; ni < 4; ++ni)
      bfr[ni] = ldfrag(Bs + (wn + ni * 16 + ln) * 32 + quad * 8);
#pragma unroll
    for (int mi = 0; mi < 4; ++mi)
#pragma unroll
      for (int ni = 0; ni < 4; ++ni)
        acc[mi][ni] = __builtin_amdgcn_mfma_f32_16x16x32_bf16(af[mi], bfr[ni], acc[mi][ni], 0, 0, 0);
  }

  float bvv[4];
#pragma unroll
  for (int ni = 0; ni < 4; ++ni) bvv[ni] = biasf[which * 1024 + n0 + wn + ni * 16 + ln];

  if (which == 2) {
#pragma unroll
    for (int mi = 0; mi < 4; ++mi)
#pragma unroll
      for (int ni = 0; ni < 4; ++ni) {
        const int col = n0 + wn + ni * 16 + ln;
        const int row0 = m0 + wm + mi * 16 + quad * 4;
        const int b = row0 >> 11, s0 = row0 & 2047;
        const int h = col >> 6, hs = col & 63;
        ushortx4 pk;
#pragma unroll
        for (int r = 0; r < 4; ++r) pk[r] = f2bf(acc[mi][ni][r] + bvv[ni]);
        *(ushortx4*)(Vt + ((size_t)((b * 16 + h) * 64 + hs)) * 2048 + s0) = pk;
      }
  } else {
    ushort_t* out = (which == 0) ? Qo : Ko;
#pragma unroll
    for (int mi = 0; mi < 4; ++mi)
#pragma unroll
      for (int ni = 0; ni < 4; ++ni) {
        const int col = n0 + wn + ni * 16 + ln;
#pragma unroll
        for (int r = 0; r < 4; ++r) {
          const int row = m0 + wm + mi * 16 + quad * 4 + r;
          out[row * 1024 + col] = f2bf((acc[mi][ni][r] + bvv[ni]) * oscale);
        }
      }
  }
}

// ---------------------------------------------------------------------------
// Flash attention v13 — flash12 shell (2 waves, stride-2 tiles, K-dbuf
// prefetch, additive combine) REBUILT on swapped 32x32x16 MFMA:
//   S = mfma_32x32x16(K, Q): D col=lane&31=q, row=crow(r,hi)=(r&3)+8(r>>2)+4hi
//   softmax lane-local; P->bf16 A-frags via 4 cvt_pk + 2 permlane32_swap per
//   k-step (m214-v22 recipe, same crow layout); PV = mfma_32x32x16(P, V).
// Replaces per tile: 64->32 MFMA issue slots, 32 perm+32 bpermute+selects ->
// 32 cvt_pk + 16 permlane; loop DS ops -> 0.  li in-lane, + shfl_xor(32) at
// end; 1/li redistributed via 64-float LDS broadcast table.
// ---------------------------------------------------------------------------
__global__ __launch_bounds__(128, 2) void flash13(
    const ushort_t* __restrict__ Q, const ushort_t* __restrict__ Kx,
    const ushort_t* __restrict__ Vt, void* __restrict__ out,
    const int* __restrict__ flag)
{
  __shared__ __attribute__((aligned(16))) float Cb[64][68];
  __shared__ float lbufW[64];
  __shared__ float ILi[64];

  const bool f32o = (*flag != 0);
  const int tid  = threadIdx.x;
  const int wave = tid >> 6;
  const int lane = tid & 63;
  const int l31 = lane & 31;
  const int hi  = lane >> 5;

#define CROW(r) (((r) & 3) + 8 * ((r) >> 2) + 4 * hi)

  // XCD-swizzled, big-chunk-first: 1024 blocks = 32 bh x 32 chunks of 64 rows.
  const int i = blockIdx.x;
  const int xcd = i & 7, j = i >> 3;
  const int bh = xcd * 4 + (j & 3);
  const int cc = 31 - (j >> 2);         // q-chunk 0..31, big first
  const int b = bh >> 4, h = bh & 15;
  const int qw = cc * 64;
  const int ntiles = cc + 1;

  const ushort_t* kbase = Kx + ((size_t)b * 2048) * 1024 + h * 64;
  const ushort_t* vbase = Vt + (size_t)bh * 64 * 2048;

  // Q as B-operand: n=q=l31, k = s*16 + hi*8 + j  (8 contiguous d per load)
  bf16x8 qf[2][4];
#pragma unroll
  for (int qq = 0; qq < 2; ++qq)
#pragma unroll
    for (int s = 0; s < 4; ++s)
      qf[qq][s] = ldfrag(Q + (size_t)(b * 2048 + qw + 32 * qq + l31) * 1024 + h * 64 + s * 16 + hi * 8);

  floatx16 ot[2][2];
#pragma unroll
  for (int qq = 0; qq < 2; ++qq)
#pragma unroll
    for (int dq = 0; dq < 2; ++dq)
#pragma unroll
      for (int r = 0; r < 16; ++r) ot[qq][dq][r] = 0.f;
  float li[2] = {0.f, 0.f};

  bf16x8 kfA[8], kfB[8], vf[8];

  // K as A-operand: m=kv=l31 (+32 for quad 1), k = s*16 + hi*8 + j
#define LOADK(KF, KV0) do {                                                   \
    const ushort_t* kp_ = kbase + (size_t)((KV0) + l31) * 1024 + hi * 8;      \
    KF[0] = ldfrag(kp_);       KF[1] = ldfrag(kp_ + 16);                      \
    KF[2] = ldfrag(kp_ + 32);  KF[3] = ldfrag(kp_ + 48);                      \
    const ushort_t* kq_ = kp_ + 32 * 1024;                                    \
    KF[4] = ldfrag(kq_);       KF[5] = ldfrag(kq_ + 16);                      \
    KF[6] = ldfrag(kq_ + 32);  KF[7] = ldfrag(kq_ + 48);                      \
  } while (0)

  // V as B-operand: n=d=32*dq+l31, k = s*16 + hi*8 + j (8 contiguous s)
#define LOADV(KV0) do {                                                       \
    const ushort_t* vp0_ = vbase + (size_t)l31 * 2048 + (KV0) + hi * 8;       \
    vf[0] = ldfrag(vp0_);       vf[1] = ldfrag(vp0_ + 16);                    \
    vf[2] = ldfrag(vp0_ + 32);  vf[3] = ldfrag(vp0_ + 48);                    \
    const ushort_t* vp1_ = vp0_ + (size_t)32 * 2048;                          \
    vf[4] = ldfrag(vp1_);       vf[5] = ldfrag(vp1_ + 16);                    \
    vf[6] = ldfrag(vp1_ + 32);  vf[7] = ldfrag(vp1_ + 48);                    \
  } while (0)

  // pack 8 p-values (one k-step) into an A-frag and feed both d-quadrants
#define PACK_PV(PARR, SH, SIDX, QQ) do {                                      \
    unsigned X_ = cvtpk_bf16(PARR[8 * (SH) + 0], PARR[8 * (SH) + 1]);         \
    unsigned Y_ = cvtpk_bf16(PARR[8 * (SH) + 2], PARR[8 * (SH) + 3]);         \
    unsigned Z_ = cvtpk_bf16(PARR[8 * (SH) + 4], PARR[8 * (SH) + 5]);         \
    unsigned W_ = cvtpk_bf16(PARR[8 * (SH) + 6], PARR[8 * (SH) + 7]);         \
    plswap(X_, Z_);                                                           \
    plswap(Y_, W_);                                                           \
    uintx4 u_ = {X_, Y_, Z_, W_};                                             \
    const bf16x8 pa_ = __builtin_bit_cast(bf16x8, u_);                        \
    ot[QQ][0] = __builtin_amdgcn_mfma_f32_32x32x16_bf16(pa_, vf[(SIDX)], ot[QQ][0], 0, 0, 0);     \
    ot[QQ][1] = __builtin_amdgcn_mfma_f32_32x32x16_bf16(pa_, vf[4 + (SIDX)], ot[QQ][1], 0, 0, 0); \
  } while (0)

#define TILE32(KF, T) do {                                                    \
    const int kv0_ = (T) * 64;                                                \
    const bool diag_ = ((T) == ntiles - 1);                                   \
    _Pragma("unroll")                                                         \
    for (int qq = 0; qq < 2; ++qq) {                                          \
      floatx16 st0, st1;                                                      \
      _Pragma("unroll")                                                       \
      for (int r = 0; r < 16; ++r) { st0[r] = 0.f; st1[r] = 0.f; }            \
      _Pragma("unroll")                                                       \
      for (int s = 0; s < 4; ++s) {                                           \
        st0 = __builtin_amdgcn_mfma_f32_32x32x16_bf16(KF[s], qf[qq][s], st0, 0, 0, 0);     \
        st1 = __builtin_amdgcn_mfma_f32_32x32x16_bf16(KF[4 + s], qf[qq][s], st1, 0, 0, 0); \
      }                                                                       \
      float p0[16], p1[16];                                                   \
      if (diag_) {                                                            \
        const int qg_ = qw + 32 * qq + l31;                                   \
        _Pragma("unroll")                                                     \
        for (int r = 0; r < 16; ++r) {                                        \
          const int kva_ = kv0_ + CROW(r);                                    \
          const float e0_ = __builtin_amdgcn_exp2f(st0[r]);                   \
          const float e1_ = __builtin_amdgcn_exp2f(st1[r]);                   \
          p0[r] = (kva_ > qg_) ? 0.f : e0_;                                   \
          p1[r] = (kva_ + 32 > qg_) ? 0.f : e1_;                              \
        }                                                                     \
      } else {                                                                \
        _Pragma("unroll")                                                     \
        for (int r = 0; r < 16; ++r) {                                        \
          p0[r] = __builtin_amdgcn_exp2f(st0[r]);                             \
          p1[r] = __builtin_amdgcn_exp2f(st1[r]);                             \
        }                                                                     \
      }                                                                       \
      float ls_ = 0.f;                                                        \
      _Pragma("unroll")                                                       \
      for (int r = 0; r < 16; ++r) ls_ += p0[r] + p1[r];                      \
      li[qq] += ls_;                                                          \
      PACK_PV(p0, 0, 0, qq);                                                  \
      PACK_PV(p0, 1, 1, qq);                                                  \
      PACK_PV(p1, 0, 2, qq);                                                  \
      PACK_PV(p1, 1, 3, qq);                                                  \
    }                                                                         \
  } while (0)

  // software pipeline: two tiles per body (kfA/kfB); next tile's K issued
  // before the current tile's compute.
  int t = wave;
  if (t < ntiles) LOADK(kfA, t * 64);
  for (; t < ntiles; t += 4) {
    LOADV(t * 64);
    if (t + 2 < ntiles) LOADK(kfB, (t + 2) * 64);
    TILE32(kfA, t);
    if (t + 2 < ntiles) {
      LOADV((t + 2) * 64);
      if (t + 4 < ntiles) LOADK(kfA, (t + 4) * 64);
      TILE32(kfB, t + 2);
    }
  }

#undef LOADK
#undef LOADV
#undef PACK_PV
#undef TILE32

  // finalize li: lane l and l^32 hold complementary kv rows of the same q
  float lf[2];
#pragma unroll
  for (int qq = 0; qq < 2; ++qq) lf[qq] = li[qq] + __shfl_xor(li[qq], 32);

  // cross-wave additive combine (both waves own the same 64 q-rows)
  if (wave == 1) {
#pragma unroll
    for (int qq = 0; qq < 2; ++qq) {
#pragma unroll
      for (int dq = 0; dq < 2; ++dq)
#pragma unroll
        for (int r = 0; r < 16; ++r)
          Cb[32 * qq + CROW(r)][32 * dq + l31] = ot[qq][dq][r];
      lbufW[32 * qq + l31] = lf[qq];   // both hi-halves write same value
    }
  }
  __syncthreads();
  if (wave == 0) {
#pragma unroll
    for (int qq = 0; qq < 2; ++qq) {
#pragma unroll
      for (int dq = 0; dq < 2; ++dq)
#pragma unroll
        for (int r = 0; r < 16; ++r)
          ot[qq][dq][r] += Cb[32 * qq + CROW(r)][32 * dq + l31];
      lf[qq] += lbufW[32 * qq + l31];
      ILi[32 * qq + l31] = 1.0f / lf[qq];
    }

#pragma unroll
    for (int qq = 0; qq < 2; ++qq) {
#pragma unroll
      for (int r = 0; r < 16; ++r) {
        const int q_ = qw + 32 * qq + CROW(r);
        const float iv = ILi[32 * qq + CROW(r)];
        if (f32o) {
          float* of = (float*)out;
#pragma unroll
          for (int dq = 0; dq < 2; ++dq)
            of[(size_t)(b * 2048 + q_) * 1024 + h * 64 + 32 * dq + l31] = ot[qq][dq][r] * iv;
        } else {
          ushort_t* ob = (ushort_t*)out;
#pragma unroll
          for (int dq = 0; dq < 2; ++dq)
            ob[(size_t)(b * 2048 + q_) * 1024 + h * 64 + 32 * dq + l31] = f2bf(ot[qq][dq][r] * iv);
        }
      }
    }
  }
#undef CROW
}

// ---------------------------------------------------------------------------
extern "C" void kernel_launch(void* const* d_in, const int* in_sizes, int n_in,
                              void* d_out, int out_size, void* d_ws, size_t ws_size,
                              hipStream_t stream) {
  char* w = (char*)d_ws;
  int* flag = (int*)w;
  size_t off = 256;
  ushort_t* xb  = (ushort_t*)(w + off); off += (size_t)4194304 * 2;
  ushort_t* wqb = (ushort_t*)(w + off); off += (size_t)1048576 * 2;
  ushort_t* wkb = (ushort_t*)(w + off); off += (size_t)1048576 * 2;
  ushort_t* wvb = (ushort_t*)(w + off); off += (size_t)1048576 * 2;
  float* biasf  = (float*)(w + off);    off += (size_t)3 * 1024 * 4;
  ushort_t* Qw  = (ushort_t*)(w + off); off += (size_t)4194304 * 2;
  ushort_t* Kw  = (ushort_t*)(w + off); off += (size_t)4194304 * 2;
  ushort_t* Vtw = (ushort_t*)(w + off);

  convert_all<<<dim3(2048, 5), 256, 0, stream>>>(
      d_in[0], d_in[1], d_in[3], d_in[5], d_in[2], d_in[4], d_in[6],
      xb, wqb, wkb, wvb, biasf, flag);
  qkv_gemm<<<dim3(8, 32, 3), 256, 0, stream>>>(xb, wqb, wkb, wvb, biasf, Qw, Kw, Vtw);
  flash13<<<1024, 128, 0, stream>>>(Qw, Kw, Vtw, d_out, flag);
}

// Round 6
// 161.202 us; speedup vs baseline: 1.2737x; 1.2737x over previous
//
#include <hip/hip_runtime.h>

typedef unsigned short ushort_t;
typedef __bf16 bf16x8 __attribute__((ext_vector_type(8)));
typedef unsigned short ushortx8 __attribute__((ext_vector_type(8)));
typedef unsigned short ushortx4 __attribute__((ext_vector_type(4)));
typedef unsigned int uintx4 __attribute__((ext_vector_type(4)));
typedef float floatx4 __attribute__((ext_vector_type(4)));
typedef float floatx16 __attribute__((ext_vector_type(16)));

__device__ inline void load16_lds(const ushort_t* g, ushort_t* l) {
  __builtin_amdgcn_global_load_lds(
      (__attribute__((address_space(1))) void*)(g),
      (__attribute__((address_space(3))) void*)(l),
      16, 0, 0);
}

__device__ inline float bf2f(ushort_t u) {
  unsigned int v = ((unsigned int)u) << 16;
  return __builtin_bit_cast(float, v);
}

__device__ inline ushort_t f2bf(float f) {
  unsigned int u = __builtin_bit_cast(unsigned int, f);
  u += 0x7fffu + ((u >> 16) & 1u);
  return (ushort_t)(u >> 16);
}

__device__ inline bf16x8 ldfrag(const ushort_t* p) {
  return __builtin_bit_cast(bf16x8, *(const ushortx8*)p);
}

// pack two f32 -> one u32 of 2 bf16 (lo = first arg); no builtin on gfx950.
__device__ inline unsigned cvtpk_bf16(float lo, float hi) {
  unsigned r;
  asm("v_cvt_pk_bf16_f32 %0, %1, %2" : "=v"(r) : "v"(lo), "v"(hi));
  return r;
}

// exchange one 32-lane half of a with the complementary half of b
// (HK/m214-v22 arg order; verified on HW with the same crow layout).
__device__ inline void plswap(unsigned& a, unsigned& b) {
  asm("v_permlane32_swap_b32 %0, %1" : "+v"(a), "+v"(b));
}

// per-wave dtype sniff; P(wrong | fp32) ~= 0.55^64 ~= 4e-17.
__device__ inline bool sniff_f32(const ushort_t* x, int lane_off) {
  float v = fabsf(bf2f(x[lane_off]));
  bool big = !(v < 1e4f);
  return __ballot(big) != 0ull;
}

// ---------------------------------------------------------------------------
// Canonicalize inputs to bf16 (x, Wq, Wk, Wv) and fp32 biases; inline sniff.
// ---------------------------------------------------------------------------
__global__ __launch_bounds__(256) void convert_all(
    const void* __restrict__ x,
    const void* __restrict__ wq, const void* __restrict__ wk, const void* __restrict__ wv,
    const void* __restrict__ bq, const void* __restrict__ bk, const void* __restrict__ bv,
    ushort_t* __restrict__ xb, ushort_t* __restrict__ wqb,
    ushort_t* __restrict__ wkb, ushort_t* __restrict__ wvb,
    float* __restrict__ biasf, int* __restrict__ flag)
{
  const bool f32 = sniff_f32((const ushort_t*)x, (int)(threadIdx.x & 63));
  const int seg = blockIdx.y;
  if (seg == 4) {
    if (blockIdx.x == 0 && threadIdx.x == 0) *flag = f32 ? 1 : 0;
    const int i = blockIdx.x * 256 + threadIdx.x;
    if (i >= 1024) return;
    const void* bs[3] = {bq, bk, bv};
#pragma unroll
    for (int k = 0; k < 3; ++k)
      biasf[k * 1024 + i] = f32 ? ((const float*)bs[k])[i] : bf2f(((const ushort_t*)bs[k])[i]);
    return;
  }
  const void* src = (seg == 0) ? x : (seg == 1) ? wq : (seg == 2) ? wk : wv;
  ushort_t* dst   = (seg == 0) ? xb : (seg == 1) ? wqb : (seg == 2) ? wkb : wvb;
  const int n = (seg == 0) ? 4194304 : 1048576;
  const int i = (blockIdx.x * 256 + threadIdx.x) * 8;
  if (i >= n) return;
  if (f32) {
    const float* s = (const float*)src + i;
    ushortx8 o;
#pragma unroll
    for (int j = 0; j < 8; ++j) o[j] = f2bf(s[j]);
    *(ushortx8*)(dst + i) = o;
  } else {
    *(ushortx8*)(dst + i) = *(const ushortx8*)((const ushort_t*)src + i);
  }
}

// ---------------------------------------------------------------------------
// QKV projection: out = x @ W^T + b; Q scaled by log2(e)/sqrt(64).
// which==2 (V) writes DIRECTLY in transposed layout Vt(bh,hs,s).
// ---------------------------------------------------------------------------
__global__ __launch_bounds__(256, 2) void qkv_gemm(
    const ushort_t* __restrict__ x,
    const ushort_t* __restrict__ Wq, const ushort_t* __restrict__ Wk,
    const ushort_t* __restrict__ Wv, const float* __restrict__ biasf,
    ushort_t* __restrict__ Qo, ushort_t* __restrict__ Ko, ushort_t* __restrict__ Vt)
{
  __shared__ __attribute__((aligned(16))) ushort_t As[128 * 32];
  __shared__ __attribute__((aligned(16))) ushort_t Bs[128 * 32];

  const int which = blockIdx.z;
  const ushort_t* W = (which == 0) ? Wq : (which == 1) ? Wk : Wv;
  const float oscale = (which == 0) ? 0.18033688011112042f : 1.0f;

  const int n0 = blockIdx.x * 128;
  const int m0 = blockIdx.y * 128;

  const int tid  = threadIdx.x;
  const int wave = tid >> 6;
  const int lane = tid & 63;
  const int ln   = lane & 15;
  const int quad = lane >> 4;
  const int wm = (wave >> 1) * 64;
  const int wn = (wave & 1) * 64;

  floatx4 acc[4][4];
#pragma unroll
  for (int i = 0; i < 4; ++i)
#pragma unroll
    for (int j = 0; j < 4; ++j) acc[i][j] = floatx4{0.f, 0.f, 0.f, 0.f};

  const int c1 = tid, c2 = tid + 256;
  const ushort_t* ga1 = x + (m0 + (c1 >> 2)) * 1024 + (c1 & 3) * 8;
  const ushort_t* ga2 = x + (m0 + (c2 >> 2)) * 1024 + (c2 & 3) * 8;
  const ushort_t* gb1 = W + (n0 + (c1 >> 2)) * 1024 + (c1 & 3) * 8;
  const ushort_t* gb2 = W + (n0 + (c2 >> 2)) * 1024 + (c2 & 3) * 8;
  ushort_t* la1 = As + wave * 512;
  ushort_t* la2 = As + 2048 + wave * 512;
  ushort_t* lb1 = Bs + wave * 512;
  ushort_t* lb2 = Bs + 2048 + wave * 512;

  for (int kt = 0; kt < 1024; kt += 32) {
    __syncthreads();
    load16_lds(ga1 + kt, la1);
    load16_lds(ga2 + kt, la2);
    load16_lds(gb1 + kt, lb1);
    load16_lds(gb2 + kt, lb2);
    __syncthreads();

    bf16x8 af[4], bfr[4];
#pragma unroll
    for (int mi = 0; mi < 4; ++mi)
      af[mi] = ldfrag(As + (wm + mi * 16 + ln) * 32 + quad * 8);
#pragma unroll
    for (int ni = 0; ni < 4; ++ni)
      bfr[ni] = ldfrag(Bs + (wn + ni * 16 + ln) * 32 + quad * 8);
#pragma unroll
    for (int mi = 0; mi < 4; ++mi)
#pragma unroll
      for (int ni = 0; ni < 4; ++ni)
        acc[mi][ni] = __builtin_amdgcn_mfma_f32_16x16x32_bf16(af[mi], bfr[ni], acc[mi][ni], 0, 0, 0);
  }

  float bvv[4];
#pragma unroll
  for (int ni = 0; ni < 4; ++ni) bvv[ni] = biasf[which * 1024 + n0 + wn + ni * 16 + ln];

  if (which == 2) {
#pragma unroll
    for (int mi = 0; mi < 4; ++mi)
#pragma unroll
      for (int ni = 0; ni < 4; ++ni) {
        const int col = n0 + wn + ni * 16 + ln;
        const int row0 = m0 + wm + mi * 16 + quad * 4;
        const int b = row0 >> 11, s0 = row0 & 2047;
        const int h = col >> 6, hs = col & 63;
        ushortx4 pk;
#pragma unroll
        for (int r = 0; r < 4; ++r) pk[r] = f2bf(acc[mi][ni][r] + bvv[ni]);
        *(ushortx4*)(Vt + ((size_t)((b * 16 + h) * 64 + hs)) * 2048 + s0) = pk;
      }
  } else {
    ushort_t* out = (which == 0) ? Qo : Ko;
#pragma unroll
    for (int mi = 0; mi < 4; ++mi)
#pragma unroll
      for (int ni = 0; ni < 4; ++ni) {
        const int col = n0 + wn + ni * 16 + ln;
#pragma unroll
        for (int r = 0; r < 4; ++r) {
          const int row = m0 + wm + mi * 16 + quad * 4 + r;
          out[row * 1024 + col] = f2bf((acc[mi][ni][r] + bvv[ni]) * oscale);
        }
      }
  }
}

// ---------------------------------------------------------------------------
// Flash attention v14 — flash13 (swapped 32x32x16, cvt_pk+permlane, zero
// loop-DS) de-spilled:
//  (1) score half-tiles processed SEQUENTIALLY (st0->p0->PV, then st1->p1->PV)
//      so only one floatx16 st + one p[16] live at a time (inner 64->32 regs);
//  (2) plain __launch_bounds__(128) — the (128,2) form produced VGPR=128 +
//      scratch both times it was used (v11, v13); v12's plain form gave 172.
// Peak live ~= 192 persistent (qf32, ot64, kfA/kfB64, vf32) + 32 inner < 256.
// ---------------------------------------------------------------------------
__global__ __launch_bounds__(128) void flash14(
    const ushort_t* __restrict__ Q, const ushort_t* __restrict__ Kx,
    const ushort_t* __restrict__ Vt, void* __restrict__ out,
    const int* __restrict__ flag)
{
  __shared__ __attribute__((aligned(16))) float Cb[64][68];
  __shared__ float lbufW[64];
  __shared__ float ILi[64];

  const bool f32o = (*flag != 0);
  const int tid  = threadIdx.x;
  const int wave = tid >> 6;
  const int lane = tid & 63;
  const int l31 = lane & 31;
  const int hi  = lane >> 5;

#define CROW(r) (((r) & 3) + 8 * ((r) >> 2) + 4 * hi)

  // XCD-swizzled, big-chunk-first: 1024 blocks = 32 bh x 32 chunks of 64 rows.
  const int i = blockIdx.x;
  const int xcd = i & 7, j = i >> 3;
  const int bh = xcd * 4 + (j & 3);
  const int cc = 31 - (j >> 2);         // q-chunk 0..31, big first
  const int b = bh >> 4, h = bh & 15;
  const int qw = cc * 64;
  const int ntiles = cc + 1;

  const ushort_t* kbase = Kx + ((size_t)b * 2048) * 1024 + h * 64;
  const ushort_t* vbase = Vt + (size_t)bh * 64 * 2048;

  // Q as B-operand: n=q=l31, k = s*16 + hi*8 + j  (8 contiguous d per load)
  bf16x8 qf[2][4];
#pragma unroll
  for (int qq = 0; qq < 2; ++qq)
#pragma unroll
    for (int s = 0; s < 4; ++s)
      qf[qq][s] = ldfrag(Q + (size_t)(b * 2048 + qw + 32 * qq + l31) * 1024 + h * 64 + s * 16 + hi * 8);

  floatx16 ot[2][2];
#pragma unroll
  for (int qq = 0; qq < 2; ++qq)
#pragma unroll
    for (int dq = 0; dq < 2; ++dq)
#pragma unroll
      for (int r = 0; r < 16; ++r) ot[qq][dq][r] = 0.f;
  float li[2] = {0.f, 0.f};

  bf16x8 kfA[8], kfB[8], vf[8];

  // K as A-operand: m=kv=l31 (+32 second half), k = s*16 + hi*8 + j
#define LOADK(KF, KV0) do {                                                   \
    const ushort_t* kp_ = kbase + (size_t)((KV0) + l31) * 1024 + hi * 8;      \
    KF[0] = ldfrag(kp_);       KF[1] = ldfrag(kp_ + 16);                      \
    KF[2] = ldfrag(kp_ + 32);  KF[3] = ldfrag(kp_ + 48);                      \
    const ushort_t* kq_ = kp_ + 32 * 1024;                                    \
    KF[4] = ldfrag(kq_);       KF[5] = ldfrag(kq_ + 16);                      \
    KF[6] = ldfrag(kq_ + 32);  KF[7] = ldfrag(kq_ + 48);                      \
  } while (0)

  // V as B-operand: n=d=32*dq+l31, k = s*16 + hi*8 + j (8 contiguous s)
#define LOADV(KV0) do {                                                       \
    const ushort_t* vp0_ = vbase + (size_t)l31 * 2048 + (KV0) + hi * 8;       \
    vf[0] = ldfrag(vp0_);       vf[1] = ldfrag(vp0_ + 16);                    \
    vf[2] = ldfrag(vp0_ + 32);  vf[3] = ldfrag(vp0_ + 48);                    \
    const ushort_t* vp1_ = vp0_ + (size_t)32 * 2048;                          \
    vf[4] = ldfrag(vp1_);       vf[5] = ldfrag(vp1_ + 16);                    \
    vf[6] = ldfrag(vp1_ + 32);  vf[7] = ldfrag(vp1_ + 48);                    \
  } while (0)

  // pack 8 p-values (one k-step) into an A-frag and feed both d-quadrants
#define PACK_PV(PARR, SH, SIDX, QQ) do {                                      \
    unsigned X_ = cvtpk_bf16(PARR[8 * (SH) + 0], PARR[8 * (SH) + 1]);         \
    unsigned Y_ = cvtpk_bf16(PARR[8 * (SH) + 2], PARR[8 * (SH) + 3]);         \
    unsigned Z_ = cvtpk_bf16(PARR[8 * (SH) + 4], PARR[8 * (SH) + 5]);         \
    unsigned W_ = cvtpk_bf16(PARR[8 * (SH) + 6], PARR[8 * (SH) + 7]);         \
    plswap(X_, Z_);                                                           \
    plswap(Y_, W_);                                                           \
    uintx4 u_ = {X_, Y_, Z_, W_};                                             \
    const bf16x8 pa_ = __builtin_bit_cast(bf16x8, u_);                        \
    ot[QQ][0] = __builtin_amdgcn_mfma_f32_32x32x16_bf16(pa_, vf[(SIDX)], ot[QQ][0], 0, 0, 0);     \
    ot[QQ][1] = __builtin_amdgcn_mfma_f32_32x32x16_bf16(pa_, vf[4 + (SIDX)], ot[QQ][1], 0, 0, 0); \
  } while (0)

  // one 32-kv half-tile: S-MFMA -> mask/exp -> li -> pack+PV.  Sequential so
  // only one st/p pair is live at any time (de-spill vs v13).
#define SHALF(KF, KOFF, KVADD, SIDX0, SIDX1, QQ) do {                         \
    floatx16 st_;                                                             \
    _Pragma("unroll")                                                         \
    for (int r = 0; r < 16; ++r) st_[r] = 0.f;                                \
    _Pragma("unroll")                                                         \
    for (int s = 0; s < 4; ++s)                                               \
      st_ = __builtin_amdgcn_mfma_f32_32x32x16_bf16(KF[(KOFF) + s], qf[QQ][s], st_, 0, 0, 0); \
    float p_[16];                                                             \
    if (diag_) {                                                              \
      const int qg_ = qw + 32 * (QQ) + l31;                                   \
      _Pragma("unroll")                                                       \
      for (int r = 0; r < 16; ++r) {                                          \
        const int kva_ = kv0_ + (KVADD) + CROW(r);                            \
        const float e_ = __builtin_amdgcn_exp2f(st_[r]);                      \
        p_[r] = (kva_ > qg_) ? 0.f : e_;                                      \
      }                                                                       \
    } else {                                                                  \
      _Pragma("unroll")                                                       \
      for (int r = 0; r < 16; ++r) p_[r] = __builtin_amdgcn_exp2f(st_[r]);    \
    }                                                                         \
    float ls_ = 0.f;                                                          \
    _Pragma("unroll")                                                         \
    for (int r = 0; r < 16; ++r) ls_ += p_[r];                                \
    li[QQ] += ls_;                                                            \
    PACK_PV(p_, 0, SIDX0, QQ);                                                \
    PACK_PV(p_, 1, SIDX1, QQ);                                                \
  } while (0)

#define TILE32(KF, T) do {                                                    \
    const int kv0_ = (T) * 64;                                                \
    const bool diag_ = ((T) == ntiles - 1);                                   \
    _Pragma("unroll")                                                         \
    for (int qq = 0; qq < 2; ++qq) {                                          \
      SHALF(KF, 0, 0, 0, 1, qq);                                              \
      SHALF(KF, 4, 32, 2, 3, qq);                                             \
    }                                                                         \
  } while (0)

  // software pipeline: two tiles per body (kfA/kfB); next tile's K issued
  // before the current tile's compute.
  int t = wave;
  if (t < ntiles) LOADK(kfA, t * 64);
  for (; t < ntiles; t += 4) {
    LOADV(t * 64);
    if (t + 2 < ntiles) LOADK(kfB, (t + 2) * 64);
    TILE32(kfA, t);
    if (t + 2 < ntiles) {
      LOADV((t + 2) * 64);
      if (t + 4 < ntiles) LOADK(kfA, (t + 4) * 64);
      TILE32(kfB, t + 2);
    }
  }

#undef LOADK
#undef LOADV
#undef PACK_PV
#undef SHALF
#undef TILE32

  // finalize li: lane l and l^32 hold complementary kv rows of the same q
  float lf[2];
#pragma unroll
  for (int qq = 0; qq < 2; ++qq) lf[qq] = li[qq] + __shfl_xor(li[qq], 32);

  // cross-wave additive combine (both waves own the same 64 q-rows)
  if (wave == 1) {
#pragma unroll
    for (int qq = 0; qq < 2; ++qq) {
#pragma unroll
      for (int dq = 0; dq < 2; ++dq)
#pragma unroll
        for (int r = 0; r < 16; ++r)
          Cb[32 * qq + CROW(r)][32 * dq + l31] = ot[qq][dq][r];
      lbufW[32 * qq + l31] = lf[qq];   // both hi-halves write same value
    }
  }
  __syncthreads();
  if (wave == 0) {
#pragma unroll
    for (int qq = 0; qq < 2; ++qq) {
#pragma unroll
      for (int dq = 0; dq < 2; ++dq)
#pragma unroll
        for (int r = 0; r < 16; ++r)
          ot[qq][dq][r] += Cb[32 * qq + CROW(r)][32 * dq + l31];
      lf[qq] += lbufW[32 * qq + l31];
      ILi[32 * qq + l31] = 1.0f / lf[qq];
    }

#pragma unroll
    for (int qq = 0; qq < 2; ++qq) {
#pragma unroll
      for (int r = 0; r < 16; ++r) {
        const int q_ = qw + 32 * qq + CROW(r);
        const float iv = ILi[32 * qq + CROW(r)];
        if (f32o) {
          float* of = (float*)out;
#pragma unroll
          for (int dq = 0; dq < 2; ++dq)
            of[(size_t)(b * 2048 + q_) * 1024 + h * 64 + 32 * dq + l31] = ot[qq][dq][r] * iv;
        } else {
          ushort_t* ob = (ushort_t*)out;
#pragma unroll
          for (int dq = 0; dq < 2; ++dq)
            ob[(size_t)(b * 2048 + q_) * 1024 + h * 64 + 32 * dq + l31] = f2bf(ot[qq][dq][r] * iv);
        }
      }
    }
  }
#undef CROW
}

// ---------------------------------------------------------------------------
extern "C" void kernel_launch(void* const* d_in, const int* in_sizes, int n_in,
                              void* d_out, int out_size, void* d_ws, size_t ws_size,
                              hipStream_t stream) {
  char* w = (char*)d_ws;
  int* flag = (int*)w;
  size_t off = 256;
  ushort_t* xb  = (ushort_t*)(w + off); off += (size_t)4194304 * 2;
  ushort_t* wqb = (ushort_t*)(w + off); off += (size_t)1048576 * 2;
  ushort_t* wkb = (ushort_t*)(w + off); off += (size_t)1048576 * 2;
  ushort_t* wvb = (ushort_t*)(w + off); off += (size_t)1048576 * 2;
  float* biasf  = (float*)(w + off);    off += (size_t)3 * 1024 * 4;
  ushort_t* Qw  = (ushort_t*)(w + off); off += (size_t)4194304 * 2;
  ushort_t* Kw  = (ushort_t*)(w + off); off += (size_t)4194304 * 2;
  ushort_t* Vtw = (ushort_t*)(w + off);

  convert_all<<<dim3(2048, 5), 256, 0, stream>>>(
      d_in[0], d_in[1], d_in[3], d_in[5], d_in[2], d_in[4], d_in[6],
      xb, wqb, wkb, wvb, biasf, flag);
  qkv_gemm<<<dim3(8, 32, 3), 256, 0, stream>>>(xb, wqb, wkb, wvb, biasf, Qw, Kw, Vtw);
  flash14<<<1024, 128, 0, stream>>>(Qw, Kw, Vtw, d_out, flag);
}